// Round 13
// baseline (474.168 us; speedup 1.0000x reference)
//
#include <hip/hip_runtime.h>
#include <math.h>

// Problem constants
#define B_N 8192
#define K_N 2048
#define D_N 768
#define R_N 32

// d_out element offsets: [x_q_st | loss | indices | dc]
#define OUT_XQ   0L
#define OUT_LOSS 6291456L
#define OUT_IDX  6291457L
#define OUT_DC   6299649L   // odd -> dc/P rows are 4B-aligned only; k==3 (mod 4) is 16B-aligned

// ---------------- emb = A @ B (f64 accumulate), h_k = ||e_k||^2  [bitwise == R4]
// + folded BT pack (blocks 0..95): BT4[i*32+r] = float4(B[r][4i..4i+3]) ----------------
__global__ __launch_bounds__(256) void k_emb(const float* __restrict__ A,
                                             const float* __restrict__ Bm,
                                             float* __restrict__ emb,
                                             float* __restrict__ hf,
                                             float* __restrict__ BT) {
    int k = blockIdx.x, t = threadIdx.x;
    if (k < 96) {   // BT pack, independent of the rest
        int j = k * 256 + t;
        int i = j >> 7;
        int rc = j & 127;
        int r = rc >> 2, c = rc & 3;
        BT[j] = Bm[r * D_N + 4 * i + c];
    }
    __shared__ float a_s[R_N];
    if (t < R_N) a_s[t] = A[k * R_N + t];
    __syncthreads();
    double hpart = 0.0;
    for (int d = t; d < D_N; d += 256) {
        double e = 0.0;
#pragma unroll
        for (int r = 0; r < R_N; ++r) e += (double)a_s[r] * (double)Bm[r * D_N + d];
        float ef = (float)e;
        emb[(long)k * D_N + d] = ef;
        hpart += (double)ef * (double)ef;
    }
    __shared__ double red[256];
    red[t] = hpart; __syncthreads();
    for (int s = 128; s > 0; s >>= 1) { if (t < s) red[t] += red[t + s]; __syncthreads(); }
    if (t == 0) hf[k] = (float)red[0];
}

// ---------------- y = x @ B^T [bitwise == R4] + fused ||x_b||^2 (f64) ----------------
__global__ __launch_bounds__(256) void k_ygemm(const float* __restrict__ x,
                                               const float* __restrict__ BT,
                                               float* __restrict__ y,
                                               double* __restrict__ A64) {
    __shared__ __align__(16) float xs[16 * D_N];     // 48 KB
    __shared__ __align__(16) float bs[48 * 128];     // 24 KB = quarter of BT
    __shared__ double normred[16][32];
    int t = threadIdx.x;
    long b0 = (long)blockIdx.x * 16;
    int h = (t >> 5) & 1, r = t & 31, w = t >> 6;
    int ra = 2 * w + h;                              // 0..7; rows ra and ra+8

    const float* xsrc = x + b0 * D_N;
#pragma unroll
    for (int j = 0; j < 12; ++j) {
        __builtin_amdgcn_global_load_lds(
            (const __attribute__((address_space(1))) void*)(xsrc + j * 1024 + t * 4),
            (__attribute__((address_space(3))) void*)(xs + j * 1024 + t * 4),
            16, 0, 0);
    }
#pragma unroll
    for (int j = 0; j < 6; ++j) {
        __builtin_amdgcn_global_load_lds(
            (const __attribute__((address_space(1))) void*)(BT + j * 1024 + t * 4),
            (__attribute__((address_space(3))) void*)(bs + j * 1024 + t * 4),
            16, 0, 0);
    }
    __syncthreads();

    const float4* xa = (const float4*)(xs + ra * D_N);
    const float4* xb = (const float4*)(xs + (ra + 8) * D_N);
    const float4* bs4 = (const float4*)bs;
    float4 a0 = make_float4(0.f, 0.f, 0.f, 0.f);
    float4 a1 = make_float4(0.f, 0.f, 0.f, 0.f);

#pragma unroll 1
    for (int p = 0; p < 4; ++p) {
        if (p > 0) {
            __syncthreads();
#pragma unroll
            for (int j = 0; j < 6; ++j) {
                __builtin_amdgcn_global_load_lds(
                    (const __attribute__((address_space(1))) void*)(BT + p * 6144 + j * 1024 + t * 4),
                    (__attribute__((address_space(3))) void*)(bs + j * 1024 + t * 4),
                    16, 0, 0);
            }
            __syncthreads();
        }
#pragma unroll
        for (int i = 0; i < 48; ++i) {
            float4 bb = bs4[i * 32 + r];
            float4 x0 = xa[p * 48 + i];
            float4 x1 = xb[p * 48 + i];
            a0.x = fmaf(x0.x, bb.x, a0.x); a0.y = fmaf(x0.y, bb.y, a0.y);
            a0.z = fmaf(x0.z, bb.z, a0.z); a0.w = fmaf(x0.w, bb.w, a0.w);
            a1.x = fmaf(x1.x, bb.x, a1.x); a1.y = fmaf(x1.y, bb.y, a1.y);
            a1.z = fmaf(x1.z, bb.z, a1.z); a1.w = fmaf(x1.w, bb.w, a1.w);
        }
    }
    y[(b0 + ra) * R_N + r] = (a0.x + a0.y) + (a0.z + a0.w);
    y[(b0 + ra + 8) * R_N + r] = (a1.x + a1.y) + (a1.z + a1.w);

    const float* xr0 = xs + ra * D_N + r;
    const float* xr1 = xs + (ra + 8) * D_N + r;
    double nv0 = 0.0, nv1 = 0.0;
#pragma unroll
    for (int q = 0; q < 24; ++q) {
        double v0 = (double)xr0[32 * q];
        double v1 = (double)xr1[32 * q];
        nv0 += v0 * v0; nv1 += v1 * v1;
    }
    normred[ra][r] = nv0; normred[ra + 8][r] = nv1;
    __syncthreads();
    if (t < 16) {
        double s = 0.0;
#pragma unroll
        for (int r2 = 0; r2 < 32; ++r2) s += normred[t][r2];
        A64[b0 + t] = s;
    }
}

// ---------------- P[b,k] = h_k - 2 y_b.A_k + fused min/max partials  [bitwise == R4] ----------------
__global__ __launch_bounds__(256) void k_pgemm(const float* __restrict__ Am,
                                               const float* __restrict__ y,
                                               const float* __restrict__ hf,
                                               const double* __restrict__ A64,
                                               float* __restrict__ P,
                                               double* __restrict__ mmpart) {
    __shared__ float As[256][33];
    __shared__ float ys[32][32];
    __shared__ double a64s[32];
    __shared__ double smn[256], smx[256];
    int t = threadIdx.x;
    int k0 = blockIdx.x * 256, b0 = blockIdx.y * 32;
    for (int i = t; i < 256 * 32; i += 256) As[i >> 5][i & 31] = Am[(long)(k0 + (i >> 5)) * R_N + (i & 31)];
    for (int i = t; i < 32 * 32; i += 256) ys[i >> 5][i & 31] = y[(long)(b0 + (i >> 5)) * R_N + (i & 31)];
    if (t < 32) a64s[t] = A64[b0 + t];
    __syncthreads();
    int k = k0 + t;
    float ar[32];
#pragma unroll
    for (int r = 0; r < 32; ++r) ar[r] = As[t][r];
    float hk = hf[k];
    double mn = 1e300, mx = -1e300;
#pragma unroll 4
    for (int b = 0; b < 32; ++b) {
        float dot = 0.f;
#pragma unroll
        for (int r = 0; r < 32; ++r) dot = fmaf(ys[b][r], ar[r], dot);
        float p = fmaf(-2.f, dot, hk);
        P[(long)(b0 + b) * K_N + k] = p;
        double dv = a64s[b] + (double)p;
        mn = fmin(mn, dv); mx = fmax(mx, dv);
    }
    smn[t] = mn; smx[t] = mx; __syncthreads();
    for (int s = 128; s > 0; s >>= 1) {
        if (t < s) { smn[t] = fmin(smn[t], smn[t + s]); smx[t] = fmax(smx[t], smx[t + s]); }
        __syncthreads();
    }
    if (t == 0) {
        int bid = blockIdx.y * gridDim.x + blockIdx.x;
        mmpart[2 * bid] = smn[0]; mmpart[2 * bid + 1] = smx[0];
    }
}

// ---------------- minmax reduce -> sc  [== R4 values] ----------------
__global__ __launch_bounds__(256) void k_minmax2(const double* __restrict__ part,
                                                 double* __restrict__ sc, int nblk) {
    int t = threadIdx.x;
    double mn = 1e300, mx = -1e300;
    for (int i = t; i < nblk; i += 256) {
        mn = fmin(mn, part[2 * i]); mx = fmax(mx, part[2 * i + 1]);
    }
    __shared__ double smn[256], smx[256];
    smn[t] = mn; smx[t] = mx; __syncthreads();
    for (int s = 128; s > 0; s >>= 1) {
        if (t < s) { smn[t] = fmin(smn[t], smn[t + s]); smx[t] = fmax(smx[t], smx[t + s]); }
        __syncthreads();
    }
    if (t == 0) {
        double mid = (smx[0] + smn[0]) * 0.5;
        double ampl = smx[0] - mid + 1e-5;
        sc[0] = mid; sc[1] = ampl; sc[2] = smn[0];
        sc[3] = 1.0 / (0.01 * ampl);   // beta
    }
}

// ---------------- first colsum (c0), gamma computed in-block  [bitwise == R4] ----------------
__global__ __launch_bounds__(256) void k_colsum(const float* __restrict__ P,
                                                const double* __restrict__ A64,
                                                const double* __restrict__ sc,
                                                float* __restrict__ part) {
    __shared__ float gs[64];
    int t = threadIdx.x;
    int k = blockIdx.x * 256 + t;
    int b0 = blockIdx.y * 64;
    if (t < 64) {
        double bet = sc[3], mnv = sc[2];
        gs[t] = (float)(bet * (mnv - A64[b0 + t]));
    }
    __syncthreads();
    float betaf = (float)sc[3];
    float s0 = 0.f, s1 = 0.f, s2 = 0.f, s3 = 0.f;
#pragma unroll
    for (int j = 0; j < 64; j += 4) {
        s0 += __expf(gs[j]     - betaf * P[(long)(b0 + j)     * K_N + k]);
        s1 += __expf(gs[j + 1] - betaf * P[(long)(b0 + j + 1) * K_N + k]);
        s2 += __expf(gs[j + 2] - betaf * P[(long)(b0 + j + 2) * K_N + k]);
        s3 += __expf(gs[j + 3] - betaf * P[(long)(b0 + j + 3) * K_N + k]);
    }
    part[(long)blockIdx.y * K_N + k] = (s0 + s1) + (s2 + s3);
}

__global__ __launch_bounds__(256) void k_colsum2(const float* __restrict__ part,
                                                 double* __restrict__ lnr64,
                                                 float* __restrict__ lnrf) {
    int k = blockIdx.x * 256 + threadIdx.x;
    double s = 0.0;
#pragma unroll 4
    for (int c = 0; c < 128; ++c) s += (double)part[(long)c * K_N + k];
    double l = -log(s);
    lnr64[k] = l; lnrf[k] = (float)l;
}

// ---------------- fused rowsum_i + colsum_{i+1}: ONE pass over P ----------------
// R13: TLP doubled. 512 threads = 8 autonomous waves x 2 rows each (same per-row
// 8-chain shuffle tree as R10-R12 -> gf bit-identical per row). R12 post-mortem:
// per-row chain ~1200cy, only 2 waves/SIMD -> stall-bound; chain shortening (f64
// log removal) was neutral, so add concurrency instead. To fit 2 blocks/CU
// (16 waves/CU = 4/SIMD): no row prefetch (pC loop-local; load latency is
// TLP-hidden at 4 waves/SIMD), __launch_bounds__(512,4) caps VGPR at 128.
// LDS deposits 7x8KB = 56KB -> 2 blocks/CU fits (112 <= 160KB). End combine:
// eight serial-2 accs in a fixed 3-level tree — same ~1e-7 f32-reassoc class
// gated in R11. If VGPR>128 or WRITE_SIZE balloons (spill) -> revert structure.
__global__ __launch_bounds__(512, 4) void k_fused(const float* __restrict__ P,
                                                  const float* __restrict__ lnrf,
                                                  const double* __restrict__ sc,
                                                  float* __restrict__ part) {
    __shared__ float4 accs[7][512];                    // waves 1..7 deposit (56 KB)
    int t = threadIdx.x, l = t & 63, wid = t >> 6;     // wave 0..7
    float betaf = (float)sc[3];
    float ln0[8], ln1[8], ln2[8], ln3[8];
#pragma unroll
    for (int w = 0; w < 8; ++w) {
        int v = w * 64 + l;
        int kb = 3 + 4 * v;
        if (v < 511) { ln0[w] = lnrf[kb]; ln1[w] = lnrf[kb + 1]; ln2[w] = lnrf[kb + 2]; ln3[w] = lnrf[kb + 3]; }
        else         { ln0[w] = lnrf[0];  ln1[w] = lnrf[1];      ln2[w] = lnrf[2];      ln3[w] = lnrf[2047]; }
    }
    float4 acc[8];
#pragma unroll
    for (int w = 0; w < 8; ++w) acc[w] = make_float4(0.f, 0.f, 0.f, 0.f);
    long rowbase = (long)blockIdx.x * 16 + wid * 2;    // this wave's 2 rows

#pragma unroll 1
    for (int rr = 0; rr < 2; ++rr) {
        const float* row = P + (rowbase + rr) * K_N;
        float4 pC[8];
#pragma unroll
        for (int w = 0; w < 8; ++w) {
            int v = w * 64 + l;
            if (v < 511) pC[w] = *(const float4*)(row + 3 + 4 * v);
            else { pC[w].x = row[0]; pC[w].y = row[1]; pC[w].z = row[2]; pC[w].w = row[2047]; }
        }
        double s[8];
#pragma unroll
        for (int w = 0; w < 8; ++w) {
            float e0 = __expf(ln0[w] - betaf * pC[w].x);
            float e1 = __expf(ln1[w] - betaf * pC[w].y);
            float e2 = __expf(ln2[w] - betaf * pC[w].z);
            float e3 = __expf(ln3[w] - betaf * pC[w].w);
            s[w] = (double)((e0 + e1) + (e2 + e3));
        }
#pragma unroll
        for (int off = 1; off < 64; off <<= 1) {
#pragma unroll
            for (int w = 0; w < 8; ++w) s[w] += __shfl_xor(s[w], off, 64);
        }
        double ss = ((s[0] + s[1]) + (s[2] + s[3])) + ((s[4] + s[5]) + (s[6] + s[7]));
        float gf = -logf((float)ss);
#pragma unroll
        for (int w = 0; w < 8; ++w) {
            acc[w].x += __expf(gf - betaf * pC[w].x);
            acc[w].y += __expf(gf - betaf * pC[w].y);
            acc[w].z += __expf(gf - betaf * pC[w].z);
            acc[w].w += __expf(gf - betaf * pC[w].w);
        }
    }
    // deposit waves 1..7, single barrier, wave 0 combines fixed 3-level tree
    if (wid > 0) {
#pragma unroll
        for (int w = 0; w < 8; ++w) accs[wid - 1][w * 64 + l] = acc[w];
    }
    __syncthreads();
    if (wid == 0) {
        float4* op = (float4*)(part + (long)blockIdx.x * K_N);
#pragma unroll
        for (int w = 0; w < 8; ++w) {
            int slot = w * 64 + l;
            float4 a1 = accs[0][slot], a2 = accs[1][slot], a3 = accs[2][slot];
            float4 a4 = accs[3][slot], a5 = accs[4][slot], a6 = accs[5][slot];
            float4 a7 = accs[6][slot];
            float4 r;
            r.x = ((acc[w].x + a1.x) + (a2.x + a3.x)) + ((a4.x + a5.x) + (a6.x + a7.x));
            r.y = ((acc[w].y + a1.y) + (a2.y + a3.y)) + ((a4.y + a5.y) + (a6.y + a7.y));
            r.z = ((acc[w].z + a1.z) + (a2.z + a3.z)) + ((a4.z + a5.z) + (a6.z + a7.z));
            r.w = ((acc[w].w + a1.w) + (a2.w + a3.w)) + ((a4.w + a5.w) + (a6.w + a7.w));
            op[slot] = r;
        }
    }
    // slot layout unchanged: vt<511 -> slots 4vt..4vt+3; vt=511 -> slots 2044..2047
}

// reduce fused partials -> lnr (coalesced; fixed f64 tree — == R8) ----------------
__global__ __launch_bounds__(256) void k_freduce(const float* __restrict__ part,
                                                 double* __restrict__ lnr64,
                                                 float* __restrict__ lnrf) {
    __shared__ double red[8][32];
    int t = threadIdx.x;
    int kk = t & 31, seg = t >> 5;                     // seg 0..7, 64 rows each
    int k = blockIdx.x * 32 + kk;
    int slot = (k >= 3 && k < 2047) ? (k - 3) : (k < 3 ? 2044 + k : 2047);
    const float* pp = part + (long)(seg * 64) * K_N + slot;
    double s = 0.0;
#pragma unroll 8
    for (int j = 0; j < 64; ++j) s += (double)pp[(long)j * K_N];
    red[seg][kk] = s;
    __syncthreads();
    if (t < 32) {
        int k2 = blockIdx.x * 32 + t;
        double v = ((red[0][t] + red[1][t]) + (red[2][t] + red[3][t]))
                 + ((red[4][t] + red[5][t]) + (red[6][t] + red[7][t]));
        double lv = -log(v);
        lnr64[k2] = lv; lnrf[k2] = (float)lv;
    }
}

// ---------------- final: wave per row — hoisted loads, argmax(f64), dc in place,
// loss via ||e-x||^2 = A64[b] + P[b,bi] (P recovered from dec), gather emb ----------------
__global__ __launch_bounds__(512) void k_final(const double* __restrict__ lnr64,
                                               const double* __restrict__ sc,
                                               const double* __restrict__ A64,
                                               const float* __restrict__ emb,
                                               float* __restrict__ out,
                                               double* __restrict__ lossp) {
    int t = threadIdx.x, l = t & 63, w = t >> 6;
    long b = (long)blockIdx.x * 8 + w;
    float* row = out + OUT_DC + b * K_N;     // P in, dc out (disjoint per wave)
    double beta = sc[3], mid = sc[0], inva = 1.0 / sc[1];
    double a64b = A64[b];
    float pe = 0.f;
    if (l < 3)   pe = row[l];
    if (l == 63) pe = row[2047];
    float4 pv[8];
#pragma unroll
    for (int c = 0; c < 8; ++c) {
        int i = l + 64 * c;
        if (i < 511) pv[c] = *(const float4*)(row + 3 + 4 * i);
    }
    double best = -1e300; int bi = 1 << 30;
    if (l < 3) {
        double p = (double)pe;
        double dec = lnr64[l] - beta * p;
        if (dec > best) { best = dec; bi = l; }
        row[l] = (float)((a64b + p - mid) * inva);
    }
#pragma unroll
    for (int c = 0; c < 8; ++c) {
        int i = l + 64 * c;
        if (i < 511) {
            int k = 3 + 4 * i;
            double p0 = pv[c].x, p1 = pv[c].y, p2 = pv[c].z, p3 = pv[c].w;
            double d0 = lnr64[k] - beta * p0;
            double d1 = lnr64[k + 1] - beta * p1;
            double d2 = lnr64[k + 2] - beta * p2;
            double d3 = lnr64[k + 3] - beta * p3;
            if (d0 > best) { best = d0; bi = k; }
            if (d1 > best) { best = d1; bi = k + 1; }
            if (d2 > best) { best = d2; bi = k + 2; }
            if (d3 > best) { best = d3; bi = k + 3; }
            float4 dcv;
            dcv.x = (float)((a64b + p0 - mid) * inva);
            dcv.y = (float)((a64b + p1 - mid) * inva);
            dcv.z = (float)((a64b + p2 - mid) * inva);
            dcv.w = (float)((a64b + p3 - mid) * inva);
            *(float4*)(row + k) = dcv;
        }
    }
    if (l == 63) {
        double p = (double)pe;
        double dec = lnr64[2047] - beta * p;
        if (dec > best) { best = dec; bi = 2047; }
        row[2047] = (float)((a64b + p - mid) * inva);
    }
#pragma unroll
    for (int off = 1; off < 64; off <<= 1) {                   // first-max: min idx on ties
        double ov = __shfl_xor(best, off, 64);
        int oi = __shfl_xor(bi, off, 64);
        if (ov > best || (ov == best && oi < bi)) { best = ov; bi = oi; }
    }
    if (l == 0) {
        out[OUT_IDX + b] = (float)bi;
        double prec = (lnr64[bi] - best) / beta;
        lossp[b] = a64b + prec;
    }
    const float4* E4 = (const float4*)(emb + (long)bi * D_N);
    float4* O4 = (float4*)(out + OUT_XQ + b * D_N);
#pragma unroll
    for (int i = 0; i < 3; ++i) O4[i * 64 + l] = E4[i * 64 + l];
}

__global__ __launch_bounds__(1024) void k_loss2(const double* __restrict__ lossp,
                                                float* __restrict__ out) {
    __shared__ double red[1024];
    int t = threadIdx.x;
    double s = 0.0;
#pragma unroll
    for (int j = 0; j < 8; ++j) s += lossp[t + 1024 * j];
    red[t] = s; __syncthreads();
    for (int st = 512; st > 0; st >>= 1) { if (t < st) red[t] += red[t + st]; __syncthreads(); }
    if (t == 0) out[OUT_LOSS] = (float)(red[0] * 1.25 / (double)((long)B_N * D_N));
}

extern "C" void kernel_launch(void* const* d_in, const int* in_sizes, int n_in,
                              void* d_out, int out_size, void* d_ws, size_t ws_size,
                              hipStream_t stream) {
    const float* x  = (const float*)d_in[0];   // [8192,768]
    const float* Am = (const float*)d_in[1];   // [2048,32]
    const float* Bm = (const float*)d_in[2];   // [32,768]
    float* out = (float*)d_out;
    float* P = out + OUT_DC;                   // P lives in dc region; k_final converts in place

    char* ws = (char*)d_ws;
    float*  emb     = (float*)(ws);                 // 6,291,456 B
    float*  y       = (float*)(ws + 6291456);       // 1,048,576 B
    float*  cs_part = (float*)(ws + 7340032);       // 128*2048*4 = 1,048,576 B
    float*  BTg     = (float*)(ws + 7340032);       // 98,304 B (overlays cs_part)
    float*  fpart   = (float*)(ws + 6291456);       // 512*2048*4 = 4,194,304 B (overlays y+cs_part)
    double* A64     = (double*)(ws + 10485760);     // 65,536 B
    float*  hf      = (float*)(ws + 10551296);      // 8,192 B
    double* lnr64   = (double*)(ws + 10592256);     // 16,384 B
    float*  lnrf    = (float*)(ws + 10608640);      // 8,192 B
    double* mmpart  = (double*)(ws + 10616832);     // 2048*2*8 = 32,768 B
    double* sc      = (double*)(ws + 10649600);     // 4 doubles
    double* lossp   = (double*)(ws + 10649856);     // 8192*8 = 65,536 B
    // total ws use ~10.7 MB

    k_emb<<<K_N, 256, 0, stream>>>(Am, Bm, emb, hf, BTg);
    k_ygemm<<<B_N / 16, 256, 0, stream>>>(x, BTg, y, A64);

    dim3 gp(K_N / 256, B_N / 32);
    k_pgemm<<<gp, 256, 0, stream>>>(Am, y, hf, A64, P, mmpart);
    k_minmax2<<<1, 256, 0, stream>>>(mmpart, sc, 2048);

    // c0 (colsum with gamma0), then 4 fused (rowsum_i + colsum_{i+1}) passes:
    // colsum x5 / rowsum x4; residual ~9e-9 << ~1e-6 decision gap (verified by
    // absmax gate in R8).
    dim3 ga(K_N / 256, 128);
    k_colsum<<<ga, 256, 0, stream>>>(P, A64, sc, cs_part);
    k_colsum2<<<K_N / 256, 256, 0, stream>>>(cs_part, lnr64, lnrf);
    for (int it = 0; it < 4; ++it) {
        k_fused<<<512, 512, 0, stream>>>(P, lnrf, sc, fpart);
        k_freduce<<<K_N / 32, 256, 0, stream>>>(fpart, lnr64, lnrf);
    }

    k_final<<<B_N / 8, 512, 0, stream>>>(lnr64, sc, A64, emb, out, lossp);
    k_loss2<<<1, 1024, 0, stream>>>(lossp, out);
}

// Round 14
// 295.434 us; speedup vs baseline: 1.6050x; 1.6050x over previous
//
#include <hip/hip_runtime.h>
#include <math.h>

// Problem constants
#define B_N 8192
#define K_N 2048
#define D_N 768
#define R_N 32

// d_out element offsets: [x_q_st | loss | indices | dc]
#define OUT_XQ   0L
#define OUT_LOSS 6291456L
#define OUT_IDX  6291457L
#define OUT_DC   6299649L   // odd -> dc/P rows are 4B-aligned only; k==3 (mod 4) is 16B-aligned

// ---------------- emb = A @ B (f64 accumulate), h_k = ||e_k||^2  [bitwise == R4]
// + folded BT pack (blocks 0..95): BT4[i*32+r] = float4(B[r][4i..4i+3]) ----------------
__global__ __launch_bounds__(256) void k_emb(const float* __restrict__ A,
                                             const float* __restrict__ Bm,
                                             float* __restrict__ emb,
                                             float* __restrict__ hf,
                                             float* __restrict__ BT) {
    int k = blockIdx.x, t = threadIdx.x;
    if (k < 96) {   // BT pack, independent of the rest
        int j = k * 256 + t;
        int i = j >> 7;
        int rc = j & 127;
        int r = rc >> 2, c = rc & 3;
        BT[j] = Bm[r * D_N + 4 * i + c];
    }
    __shared__ float a_s[R_N];
    if (t < R_N) a_s[t] = A[k * R_N + t];
    __syncthreads();
    double hpart = 0.0;
    for (int d = t; d < D_N; d += 256) {
        double e = 0.0;
#pragma unroll
        for (int r = 0; r < R_N; ++r) e += (double)a_s[r] * (double)Bm[r * D_N + d];
        float ef = (float)e;
        emb[(long)k * D_N + d] = ef;
        hpart += (double)ef * (double)ef;
    }
    __shared__ double red[256];
    red[t] = hpart; __syncthreads();
    for (int s = 128; s > 0; s >>= 1) { if (t < s) red[t] += red[t + s]; __syncthreads(); }
    if (t == 0) hf[k] = (float)red[0];
}

// ---------------- y = x @ B^T [bitwise == R4] + fused ||x_b||^2 (f64) ----------------
__global__ __launch_bounds__(256) void k_ygemm(const float* __restrict__ x,
                                               const float* __restrict__ BT,
                                               float* __restrict__ y,
                                               double* __restrict__ A64) {
    __shared__ __align__(16) float xs[16 * D_N];     // 48 KB
    __shared__ __align__(16) float bs[48 * 128];     // 24 KB = quarter of BT
    __shared__ double normred[16][32];
    int t = threadIdx.x;
    long b0 = (long)blockIdx.x * 16;
    int h = (t >> 5) & 1, r = t & 31, w = t >> 6;
    int ra = 2 * w + h;                              // 0..7; rows ra and ra+8

    const float* xsrc = x + b0 * D_N;
#pragma unroll
    for (int j = 0; j < 12; ++j) {
        __builtin_amdgcn_global_load_lds(
            (const __attribute__((address_space(1))) void*)(xsrc + j * 1024 + t * 4),
            (__attribute__((address_space(3))) void*)(xs + j * 1024 + t * 4),
            16, 0, 0);
    }
#pragma unroll
    for (int j = 0; j < 6; ++j) {
        __builtin_amdgcn_global_load_lds(
            (const __attribute__((address_space(1))) void*)(BT + j * 1024 + t * 4),
            (__attribute__((address_space(3))) void*)(bs + j * 1024 + t * 4),
            16, 0, 0);
    }
    __syncthreads();

    const float4* xa = (const float4*)(xs + ra * D_N);
    const float4* xb = (const float4*)(xs + (ra + 8) * D_N);
    const float4* bs4 = (const float4*)bs;
    float4 a0 = make_float4(0.f, 0.f, 0.f, 0.f);
    float4 a1 = make_float4(0.f, 0.f, 0.f, 0.f);

#pragma unroll 1
    for (int p = 0; p < 4; ++p) {
        if (p > 0) {
            __syncthreads();
#pragma unroll
            for (int j = 0; j < 6; ++j) {
                __builtin_amdgcn_global_load_lds(
                    (const __attribute__((address_space(1))) void*)(BT + p * 6144 + j * 1024 + t * 4),
                    (__attribute__((address_space(3))) void*)(bs + j * 1024 + t * 4),
                    16, 0, 0);
            }
            __syncthreads();
        }
#pragma unroll
        for (int i = 0; i < 48; ++i) {
            float4 bb = bs4[i * 32 + r];
            float4 x0 = xa[p * 48 + i];
            float4 x1 = xb[p * 48 + i];
            a0.x = fmaf(x0.x, bb.x, a0.x); a0.y = fmaf(x0.y, bb.y, a0.y);
            a0.z = fmaf(x0.z, bb.z, a0.z); a0.w = fmaf(x0.w, bb.w, a0.w);
            a1.x = fmaf(x1.x, bb.x, a1.x); a1.y = fmaf(x1.y, bb.y, a1.y);
            a1.z = fmaf(x1.z, bb.z, a1.z); a1.w = fmaf(x1.w, bb.w, a1.w);
        }
    }
    y[(b0 + ra) * R_N + r] = (a0.x + a0.y) + (a0.z + a0.w);
    y[(b0 + ra + 8) * R_N + r] = (a1.x + a1.y) + (a1.z + a1.w);

    const float* xr0 = xs + ra * D_N + r;
    const float* xr1 = xs + (ra + 8) * D_N + r;
    double nv0 = 0.0, nv1 = 0.0;
#pragma unroll
    for (int q = 0; q < 24; ++q) {
        double v0 = (double)xr0[32 * q];
        double v1 = (double)xr1[32 * q];
        nv0 += v0 * v0; nv1 += v1 * v1;
    }
    normred[ra][r] = nv0; normred[ra + 8][r] = nv1;
    __syncthreads();
    if (t < 16) {
        double s = 0.0;
#pragma unroll
        for (int r2 = 0; r2 < 32; ++r2) s += normred[t][r2];
        A64[b0 + t] = s;
    }
}

// ---------------- P[b,k] = h_k - 2 y_b.A_k + fused min/max partials  [bitwise == R4] ----------------
__global__ __launch_bounds__(256) void k_pgemm(const float* __restrict__ Am,
                                               const float* __restrict__ y,
                                               const float* __restrict__ hf,
                                               const double* __restrict__ A64,
                                               float* __restrict__ P,
                                               double* __restrict__ mmpart) {
    __shared__ float As[256][33];
    __shared__ float ys[32][32];
    __shared__ double a64s[32];
    __shared__ double smn[256], smx[256];
    int t = threadIdx.x;
    int k0 = blockIdx.x * 256, b0 = blockIdx.y * 32;
    for (int i = t; i < 256 * 32; i += 256) As[i >> 5][i & 31] = Am[(long)(k0 + (i >> 5)) * R_N + (i & 31)];
    for (int i = t; i < 32 * 32; i += 256) ys[i >> 5][i & 31] = y[(long)(b0 + (i >> 5)) * R_N + (i & 31)];
    if (t < 32) a64s[t] = A64[b0 + t];
    __syncthreads();
    int k = k0 + t;
    float ar[32];
#pragma unroll
    for (int r = 0; r < 32; ++r) ar[r] = As[t][r];
    float hk = hf[k];
    double mn = 1e300, mx = -1e300;
#pragma unroll 4
    for (int b = 0; b < 32; ++b) {
        float dot = 0.f;
#pragma unroll
        for (int r = 0; r < 32; ++r) dot = fmaf(ys[b][r], ar[r], dot);
        float p = fmaf(-2.f, dot, hk);
        P[(long)(b0 + b) * K_N + k] = p;
        double dv = a64s[b] + (double)p;
        mn = fmin(mn, dv); mx = fmax(mx, dv);
    }
    smn[t] = mn; smx[t] = mx; __syncthreads();
    for (int s = 128; s > 0; s >>= 1) {
        if (t < s) { smn[t] = fmin(smn[t], smn[t + s]); smx[t] = fmax(smx[t], smx[t + s]); }
        __syncthreads();
    }
    if (t == 0) {
        int bid = blockIdx.y * gridDim.x + blockIdx.x;
        mmpart[2 * bid] = smn[0]; mmpart[2 * bid + 1] = smx[0];
    }
}

// ---------------- minmax reduce -> sc  [== R4 values] ----------------
__global__ __launch_bounds__(256) void k_minmax2(const double* __restrict__ part,
                                                 double* __restrict__ sc, int nblk) {
    int t = threadIdx.x;
    double mn = 1e300, mx = -1e300;
    for (int i = t; i < nblk; i += 256) {
        mn = fmin(mn, part[2 * i]); mx = fmax(mx, part[2 * i + 1]);
    }
    __shared__ double smn[256], smx[256];
    smn[t] = mn; smx[t] = mx; __syncthreads();
    for (int s = 128; s > 0; s >>= 1) {
        if (t < s) { smn[t] = fmin(smn[t], smn[t + s]); smx[t] = fmax(smx[t], smx[t + s]); }
        __syncthreads();
    }
    if (t == 0) {
        double mid = (smx[0] + smn[0]) * 0.5;
        double ampl = smx[0] - mid + 1e-5;
        sc[0] = mid; sc[1] = ampl; sc[2] = smn[0];
        sc[3] = 1.0 / (0.01 * ampl);   // beta
    }
}

// ---------------- first colsum (c0), gamma computed in-block  [bitwise == R4] ----------------
__global__ __launch_bounds__(256) void k_colsum(const float* __restrict__ P,
                                                const double* __restrict__ A64,
                                                const double* __restrict__ sc,
                                                float* __restrict__ part) {
    __shared__ float gs[64];
    int t = threadIdx.x;
    int k = blockIdx.x * 256 + t;
    int b0 = blockIdx.y * 64;
    if (t < 64) {
        double bet = sc[3], mnv = sc[2];
        gs[t] = (float)(bet * (mnv - A64[b0 + t]));
    }
    __syncthreads();
    float betaf = (float)sc[3];
    float s0 = 0.f, s1 = 0.f, s2 = 0.f, s3 = 0.f;
#pragma unroll
    for (int j = 0; j < 64; j += 4) {
        s0 += __expf(gs[j]     - betaf * P[(long)(b0 + j)     * K_N + k]);
        s1 += __expf(gs[j + 1] - betaf * P[(long)(b0 + j + 1) * K_N + k]);
        s2 += __expf(gs[j + 2] - betaf * P[(long)(b0 + j + 2) * K_N + k]);
        s3 += __expf(gs[j + 3] - betaf * P[(long)(b0 + j + 3) * K_N + k]);
    }
    part[(long)blockIdx.y * K_N + k] = (s0 + s1) + (s2 + s3);
}

__global__ __launch_bounds__(256) void k_colsum2(const float* __restrict__ part,
                                                 double* __restrict__ lnr64,
                                                 float* __restrict__ lnrf) {
    int k = blockIdx.x * 256 + threadIdx.x;
    double s = 0.0;
#pragma unroll 4
    for (int c = 0; c < 128; ++c) s += (double)part[(long)c * K_N + k];
    double l = -log(s);
    lnr64[k] = l; lnrf[k] = (float)l;
}

// ---------------- fused rowsum_i + colsum_{i+1}: ONE pass over P ----------------
// R14: k_fused reverted to the R12 form VERBATIM (proven 322us; R13's
// __launch_bounds__(512,4) forced VGPR=64 -> 103MB scratch spill — ledger rule:
// never force occupancy via launch-bounds on a register-heavy body).
// Model (R12 neutral chain-shortening + R13 stream rates): this kernel is
// P-STREAM BANDWIDTH-BOUND (~2.8 TB/s effective over 64MB/pass), so the lever
// is FEWER PASSES, not more TLP — hence 3 fused passes below.
__global__ __launch_bounds__(256) void k_fused(const float* __restrict__ P,
                                               const float* __restrict__ lnrf,
                                               const double* __restrict__ sc,
                                               float* __restrict__ part) {
    __shared__ float4 accs[3][512];                    // waves 1..3 deposit (24 KB)
    int t = threadIdx.x, l = t & 63, wid = t >> 6;     // wave 0..3
    float betaf = (float)sc[3];
    float ln0[8], ln1[8], ln2[8], ln3[8];
    int kb[8];
#pragma unroll
    for (int w = 0; w < 8; ++w) {
        int v = w * 64 + l;
        kb[w] = 3 + 4 * v;
        if (v < 511) { ln0[w] = lnrf[kb[w]]; ln1[w] = lnrf[kb[w] + 1]; ln2[w] = lnrf[kb[w] + 2]; ln3[w] = lnrf[kb[w] + 3]; }
        else         { ln0[w] = lnrf[0];     ln1[w] = lnrf[1];         ln2[w] = lnrf[2];         ln3[w] = lnrf[2047]; }
    }
    float4 acc[8];
#pragma unroll
    for (int w = 0; w < 8; ++w) acc[w] = make_float4(0.f, 0.f, 0.f, 0.f);
    long rowbase = (long)blockIdx.x * 16 + wid * 4;    // this wave's 4 rows

    float4 pC[8], pN[8];
    {
        const float* row0 = P + rowbase * K_N;
#pragma unroll
        for (int w = 0; w < 8; ++w) {
            if (w * 64 + l < 511) pC[w] = *(const float4*)(row0 + kb[w]);
            else { pC[w].x = row0[0]; pC[w].y = row0[1]; pC[w].z = row0[2]; pC[w].w = row0[2047]; }
        }
    }
#pragma unroll 1
    for (int rr = 0; rr < 4; ++rr) {
        if (rr < 3) {
            const float* rowN = P + (rowbase + rr + 1) * K_N;
#pragma unroll
            for (int w = 0; w < 8; ++w) {
                if (w * 64 + l < 511) pN[w] = *(const float4*)(rowN + kb[w]);
                else { pN[w].x = rowN[0]; pN[w].y = rowN[1]; pN[w].z = rowN[2]; pN[w].w = rowN[2047]; }
            }
        }
        double s[8];
#pragma unroll
        for (int w = 0; w < 8; ++w) {
            float e0 = __expf(ln0[w] - betaf * pC[w].x);
            float e1 = __expf(ln1[w] - betaf * pC[w].y);
            float e2 = __expf(ln2[w] - betaf * pC[w].z);
            float e3 = __expf(ln3[w] - betaf * pC[w].w);
            s[w] = (double)((e0 + e1) + (e2 + e3));
        }
#pragma unroll
        for (int off = 1; off < 64; off <<= 1) {
#pragma unroll
            for (int w = 0; w < 8; ++w) s[w] += __shfl_xor(s[w], off, 64);
        }
        double ss = ((s[0] + s[1]) + (s[2] + s[3])) + ((s[4] + s[5]) + (s[6] + s[7]));
        float gf = -logf((float)ss);
#pragma unroll
        for (int w = 0; w < 8; ++w) {
            acc[w].x += __expf(gf - betaf * pC[w].x);
            acc[w].y += __expf(gf - betaf * pC[w].y);
            acc[w].z += __expf(gf - betaf * pC[w].z);
            acc[w].w += __expf(gf - betaf * pC[w].w);
        }
#pragma unroll
        for (int w = 0; w < 8; ++w) pC[w] = pN[w];
    }
    // deposit waves 1..3, single barrier, wave 0 combines ((w0+w1)+(w2+w3))
    if (wid > 0) {
#pragma unroll
        for (int w = 0; w < 8; ++w) accs[wid - 1][w * 64 + l] = acc[w];
    }
    __syncthreads();
    if (wid == 0) {
        float4* op = (float4*)(part + (long)blockIdx.x * K_N);
#pragma unroll
        for (int w = 0; w < 8; ++w) {
            int slot = w * 64 + l;
            float4 a1 = accs[0][slot], a2 = accs[1][slot], a3 = accs[2][slot];
            float4 r;
            r.x = (acc[w].x + a1.x) + (a2.x + a3.x);
            r.y = (acc[w].y + a1.y) + (a2.y + a3.y);
            r.z = (acc[w].z + a1.z) + (a2.z + a3.z);
            r.w = (acc[w].w + a1.w) + (a2.w + a3.w);
            op[slot] = r;
        }
    }
    // slot layout unchanged: vt<511 -> slots 4vt..4vt+3; vt=511 -> slots 2044..2047
}

// reduce fused partials -> lnr (coalesced; fixed f64 tree — == R8) ----------------
__global__ __launch_bounds__(256) void k_freduce(const float* __restrict__ part,
                                                 double* __restrict__ lnr64,
                                                 float* __restrict__ lnrf) {
    __shared__ double red[8][32];
    int t = threadIdx.x;
    int kk = t & 31, seg = t >> 5;                     // seg 0..7, 64 rows each
    int k = blockIdx.x * 32 + kk;
    int slot = (k >= 3 && k < 2047) ? (k - 3) : (k < 3 ? 2044 + k : 2047);
    const float* pp = part + (long)(seg * 64) * K_N + slot;
    double s = 0.0;
#pragma unroll 8
    for (int j = 0; j < 64; ++j) s += (double)pp[(long)j * K_N];
    red[seg][kk] = s;
    __syncthreads();
    if (t < 32) {
        int k2 = blockIdx.x * 32 + t;
        double v = ((red[0][t] + red[1][t]) + (red[2][t] + red[3][t]))
                 + ((red[4][t] + red[5][t]) + (red[6][t] + red[7][t]));
        double lv = -log(v);
        lnr64[k2] = lv; lnrf[k2] = (float)lv;
    }
}

// ---------------- final: wave per row — hoisted loads, argmax(f64), dc in place,
// loss via ||e-x||^2 = A64[b] + P[b,bi] (P recovered from dec), gather emb ----------------
__global__ __launch_bounds__(512) void k_final(const double* __restrict__ lnr64,
                                               const double* __restrict__ sc,
                                               const double* __restrict__ A64,
                                               const float* __restrict__ emb,
                                               float* __restrict__ out,
                                               double* __restrict__ lossp) {
    int t = threadIdx.x, l = t & 63, w = t >> 6;
    long b = (long)blockIdx.x * 8 + w;
    float* row = out + OUT_DC + b * K_N;     // P in, dc out (disjoint per wave)
    double beta = sc[3], mid = sc[0], inva = 1.0 / sc[1];
    double a64b = A64[b];
    float pe = 0.f;
    if (l < 3)   pe = row[l];
    if (l == 63) pe = row[2047];
    float4 pv[8];
#pragma unroll
    for (int c = 0; c < 8; ++c) {
        int i = l + 64 * c;
        if (i < 511) pv[c] = *(const float4*)(row + 3 + 4 * i);
    }
    double best = -1e300; int bi = 1 << 30;
    if (l < 3) {
        double p = (double)pe;
        double dec = lnr64[l] - beta * p;
        if (dec > best) { best = dec; bi = l; }
        row[l] = (float)((a64b + p - mid) * inva);
    }
#pragma unroll
    for (int c = 0; c < 8; ++c) {
        int i = l + 64 * c;
        if (i < 511) {
            int k = 3 + 4 * i;
            double p0 = pv[c].x, p1 = pv[c].y, p2 = pv[c].z, p3 = pv[c].w;
            double d0 = lnr64[k] - beta * p0;
            double d1 = lnr64[k + 1] - beta * p1;
            double d2 = lnr64[k + 2] - beta * p2;
            double d3 = lnr64[k + 3] - beta * p3;
            if (d0 > best) { best = d0; bi = k; }
            if (d1 > best) { best = d1; bi = k + 1; }
            if (d2 > best) { best = d2; bi = k + 2; }
            if (d3 > best) { best = d3; bi = k + 3; }
            float4 dcv;
            dcv.x = (float)((a64b + p0 - mid) * inva);
            dcv.y = (float)((a64b + p1 - mid) * inva);
            dcv.z = (float)((a64b + p2 - mid) * inva);
            dcv.w = (float)((a64b + p3 - mid) * inva);
            *(float4*)(row + k) = dcv;
        }
    }
    if (l == 63) {
        double p = (double)pe;
        double dec = lnr64[2047] - beta * p;
        if (dec > best) { best = dec; bi = 2047; }
        row[2047] = (float)((a64b + p - mid) * inva);
    }
#pragma unroll
    for (int off = 1; off < 64; off <<= 1) {                   // first-max: min idx on ties
        double ov = __shfl_xor(best, off, 64);
        int oi = __shfl_xor(bi, off, 64);
        if (ov > best || (ov == best && oi < bi)) { best = ov; bi = oi; }
    }
    if (l == 0) {
        out[OUT_IDX + b] = (float)bi;
        double prec = (lnr64[bi] - best) / beta;
        lossp[b] = a64b + prec;
    }
    const float4* E4 = (const float4*)(emb + (long)bi * D_N);
    float4* O4 = (float4*)(out + OUT_XQ + b * D_N);
#pragma unroll
    for (int i = 0; i < 3; ++i) O4[i * 64 + l] = E4[i * 64 + l];
}

__global__ __launch_bounds__(1024) void k_loss2(const double* __restrict__ lossp,
                                                float* __restrict__ out) {
    __shared__ double red[1024];
    int t = threadIdx.x;
    double s = 0.0;
#pragma unroll
    for (int j = 0; j < 8; ++j) s += lossp[t + 1024 * j];
    red[t] = s; __syncthreads();
    for (int st = 512; st > 0; st >>= 1) { if (t < st) red[t] += red[t + st]; __syncthreads(); }
    if (t == 0) out[OUT_LOSS] = (float)(red[0] * 1.25 / (double)((long)B_N * D_N));
}

extern "C" void kernel_launch(void* const* d_in, const int* in_sizes, int n_in,
                              void* d_out, int out_size, void* d_ws, size_t ws_size,
                              hipStream_t stream) {
    const float* x  = (const float*)d_in[0];   // [8192,768]
    const float* Am = (const float*)d_in[1];   // [2048,32]
    const float* Bm = (const float*)d_in[2];   // [32,768]
    float* out = (float*)d_out;
    float* P = out + OUT_DC;                   // P lives in dc region; k_final converts in place

    char* ws = (char*)d_ws;
    float*  emb     = (float*)(ws);                 // 6,291,456 B
    float*  y       = (float*)(ws + 6291456);       // 1,048,576 B
    float*  cs_part = (float*)(ws + 7340032);       // 128*2048*4 = 1,048,576 B
    float*  BTg     = (float*)(ws + 7340032);       // 98,304 B (overlays cs_part)
    float*  fpart   = (float*)(ws + 6291456);       // 512*2048*4 = 4,194,304 B (overlays y+cs_part)
    double* A64     = (double*)(ws + 10485760);     // 65,536 B
    float*  hf      = (float*)(ws + 10551296);      // 8,192 B
    double* lnr64   = (double*)(ws + 10592256);     // 16,384 B
    float*  lnrf    = (float*)(ws + 10608640);      // 8,192 B
    double* mmpart  = (double*)(ws + 10616832);     // 2048*2*8 = 32,768 B
    double* sc      = (double*)(ws + 10649600);     // 4 doubles
    double* lossp   = (double*)(ws + 10649856);     // 8192*8 = 65,536 B
    // total ws use ~10.7 MB

    k_emb<<<K_N, 256, 0, stream>>>(Am, Bm, emb, hf, BTg);
    k_ygemm<<<B_N / 16, 256, 0, stream>>>(x, BTg, y, A64);

    dim3 gp(K_N / 256, B_N / 32);
    k_pgemm<<<gp, 256, 0, stream>>>(Am, y, hf, A64, P, mmpart);
    k_minmax2<<<1, 256, 0, stream>>>(mmpart, sc, 2048);

    // c0 (colsum with gamma0), then 3 fused (rowsum_i + colsum_{i+1}) passes:
    // colsum x4 / rowsum x3. Residual ~0.022^3*C ~ 4e-7 vs ~1e-6 decision gap
    // (margin ~2.5x; R8's 5->4 drop at 100x margin passed with absmax bit-equal).
    // GATED: if passed=false or absmax jumps, revert to 4 passes.
    dim3 ga(K_N / 256, 128);
    k_colsum<<<ga, 256, 0, stream>>>(P, A64, sc, cs_part);
    k_colsum2<<<K_N / 256, 256, 0, stream>>>(cs_part, lnr64, lnrf);
    for (int it = 0; it < 3; ++it) {
        k_fused<<<512, 256, 0, stream>>>(P, lnrf, sc, fpart);
        k_freduce<<<K_N / 32, 256, 0, stream>>>(fpart, lnr64, lnrf);
    }

    k_final<<<B_N / 8, 512, 0, stream>>>(lnr64, sc, A64, emb, out, lossp);
    k_loss2<<<1, 1024, 0, stream>>>(lossp, out);
}